// Round 3
// baseline (469.464 us; speedup 1.0000x reference)
//
#include <hip/hip_runtime.h>
#include <hip/hip_bf16.h>

#define NB 16
#define CDIM 256
#define NHEADS 8
#define DH 32
#define NSP 4096
#define O3 768

typedef __bf16 bf16;
typedef bf16 bf16x4 __attribute__((ext_vector_type(4)));
typedef bf16 bf16x8 __attribute__((ext_vector_type(8)));
typedef float f32x4 __attribute__((ext_vector_type(4)));

static __device__ __forceinline__ float bf2f(bf16 x){ return (float)x; }
static __device__ __forceinline__ bf16 f2bf(float x){ return (bf16)x; }

// ---------------- K0: transpose+convert x[b][c][n] (fp32) -> xT[b][n][c] (bf16) ----------------
__global__ void k_transpose(const float* __restrict__ x, bf16* __restrict__ xT){
    __shared__ bf16 tile[64][72];
    int b = blockIdx.z;
    int c0 = blockIdx.y * 64;
    int n0 = blockIdx.x * 64;
    int t = threadIdx.x;
    const float* xb = x + (size_t)b * CDIM * NSP;
    #pragma unroll
    for (int i = 0; i < 4; ++i){
        int lin = i*256 + t;
        int c = lin >> 4;           // 0..63
        int n4 = (lin & 15) * 4;    // 0..60
        f32x4 f = *(const f32x4*)(xb + (size_t)(c0 + c)*NSP + n0 + n4);
        bf16x4 v4;
        #pragma unroll
        for (int j = 0; j < 4; ++j) v4[j] = f2bf(f[j]);
        *(bf16x4*)&tile[c][n4] = v4;
    }
    __syncthreads();
    bf16* xTb = xT + (size_t)b * NSP * CDIM;
    #pragma unroll
    for (int i = 0; i < 2; ++i){
        int lin = i*256 + t;
        int n = lin >> 3;           // 0..63
        int c8 = (lin & 7) * 8;     // 0..56
        bf16x8 v;
        #pragma unroll
        for (int j = 0; j < 8; ++j) v[j] = tile[c8+j][n];
        *(bf16x8*)(xTb + (size_t)(n0+n)*CDIM + c0 + c8) = v;
    }
}

// ---------------- K1: qkv GEMM  (M=768, K=256, N=4096 per batch) ----------------
// A = w_qkv [768][256] fp32 (convert to bf16 in staging), B = xT[b][n][256] bf16.
// m-tiles 0..1 (q rows) write TRANSPOSED to qT[b][n][c]; m-tiles 2..5 write kv[b][c][n].
#define LDT 40   // padded LDS row stride in bf16 (80B, 16B-aligned)
__global__ __launch_bounds__(256) void k_qkv(const float* __restrict__ w,
                                             const bf16* __restrict__ xT,
                                             bf16* __restrict__ qT,
                                             bf16* __restrict__ kv){
    __shared__ bf16 As[128*LDT];
    __shared__ bf16 Bs[128*LDT];
    int m0 = blockIdx.x * 128;           // 6 tiles over 768
    int b  = blockIdx.y >> 5;            // 32 n-tiles per batch
    int n0 = (blockIdx.y & 31) * 128;
    int t = threadIdx.x;
    int wv = t >> 6, lane = t & 63;
    f32x4 acc[2][8];
    #pragma unroll
    for (int i=0;i<16;i++) ((f32x4*)acc)[i] = (f32x4){0.f,0.f,0.f,0.f};

    const bf16* xb = xT + ((size_t)b*NSP + n0)*CDIM;
    for (int k0 = 0; k0 < CDIM; k0 += 32){
        __syncthreads();
        #pragma unroll
        for (int i=0;i<2;i++){
            int lin = i*256 + t; int r = lin>>2; int c8 = (lin&3)*8;
            const float* wp = w + (size_t)(m0+r)*CDIM + k0 + c8;
            f32x4 a0 = *(const f32x4*)wp;
            f32x4 a1 = *(const f32x4*)(wp + 4);
            bf16x8 av;
            #pragma unroll
            for (int j=0;j<4;j++){ av[j] = f2bf(a0[j]); av[4+j] = f2bf(a1[j]); }
            *(bf16x8*)&As[r*LDT + c8] = av;
            *(bf16x8*)&Bs[r*LDT + c8] = *(const bf16x8*)(xb + (size_t)r*CDIM + k0 + c8);
        }
        __syncthreads();
        bf16x8 af[2], bfr[8];
        #pragma unroll
        for (int mi=0; mi<2; mi++)
            af[mi] = *(const bf16x8*)&As[(wv*32 + mi*16 + (lane&15))*LDT + (lane>>4)*8];
        #pragma unroll
        for (int ni=0; ni<8; ni++)
            bfr[ni] = *(const bf16x8*)&Bs[(ni*16 + (lane&15))*LDT + (lane>>4)*8];
        #pragma unroll
        for (int mi=0; mi<2; mi++)
            #pragma unroll
            for (int ni=0; ni<8; ni++)
                acc[mi][ni] = __builtin_amdgcn_mfma_f32_16x16x32_bf16(af[mi], bfr[ni], acc[mi][ni], 0, 0, 0);
    }
    if (m0 < 256){
        // q: write transposed [b][n][o], o in [0,256). 4 o-contiguous accs -> one 8B store.
        bf16* qTb = qT + (size_t)b * NSP * CDIM;
        #pragma unroll
        for (int mi=0;mi<2;mi++){
            #pragma unroll
            for (int ni=0;ni<8;ni++){
                int n = n0 + ni*16 + (lane&15);
                int o = m0 + wv*32 + mi*16 + (lane>>4)*4;
                bf16x4 v4;
                #pragma unroll
                for (int r=0;r<4;r++) v4[r] = f2bf(acc[mi][ni][r]);
                *(bf16x4*)(qTb + (size_t)n*CDIM + o) = v4;
            }
        }
    } else {
        // k/v: write [b][c][n], c = m0-256 .. (k: c<256, v: c>=256)
        bf16* kvb = kv + (size_t)b * 512 * NSP;
        int c0t = m0 - 256;
        #pragma unroll
        for (int mi=0;mi<2;mi++){
            #pragma unroll
            for (int ni=0;ni<8;ni++){
                int col = n0 + ni*16 + (lane&15);
                #pragma unroll
                for (int r=0;r<4;r++){
                    int c = c0t + wv*32 + mi*16 + (lane>>4)*4 + r;
                    kvb[(size_t)c*NSP + col] = f2bf(acc[mi][ni][r]);
                }
            }
        }
    }
}

// ---------------- K2: q softmax over d (32 contiguous channels), in-place on qT ----------------
__global__ void k_qsoftmax(bf16* __restrict__ qT){
    int t = threadIdx.x;
    // each thread: one (n, head) -> 32 contiguous bf16
    size_t row = (size_t)blockIdx.x*32 + (t>>3);   // global n index over [0, NB*NSP)
    bf16* p = qT + row*CDIM + (size_t)(t&7)*DH;
    float v[32]; float mx = -1e30f;
    #pragma unroll
    for (int g=0; g<4; g++){
        bf16x8 i8 = *(const bf16x8*)(p + g*8);
        #pragma unroll
        for (int j=0;j<8;j++){ v[g*8+j] = bf2f(i8[j]); mx = fmaxf(mx, v[g*8+j]); }
    }
    float s = 0.f;
    #pragma unroll
    for (int d=0; d<32; d++){ v[d] = __expf(v[d]-mx); s += v[d]; }
    float inv = 1.f/s;
    #pragma unroll
    for (int g=0; g<4; g++){
        bf16x8 o8;
        #pragma unroll
        for (int j=0;j<8;j++) o8[j] = f2bf(v[g*8+j]*inv);
        *(bf16x8*)(p + g*8) = o8;
    }
}

// ---------------- K3: k softmax over w (in-place on kv k-section) ----------------
__global__ void k_ksoftmax(bf16* __restrict__ kv){
    int gid = blockIdx.x*4 + (threadIdx.x>>6);
    int lane = threadIdx.x & 63;
    int b = gid >> 14;            // 256 channels * 64 x-rows per batch
    int rem = gid & 16383;
    int c = rem >> 6;
    int hrow = rem & 63;
    bf16* p = kv + ((size_t)b*512 + c)*NSP + hrow*64 + lane;
    float v = bf2f(*p);
    float m = v;
    #pragma unroll
    for (int off=32; off; off>>=1) m = fmaxf(m, __shfl_xor(m, off, 64));
    float e = __expf(v - m);
    float s = e;
    #pragma unroll
    for (int off=32; off; off>>=1) s += __shfl_xor(s, off, 64);
    *p = f2bf(e/s);
}

// ---------------- K4: context[b,h,d,e] = sum_n k~[d,n] * v[e,n]  (fp32) ----------------
__global__ void k_context(const bf16* __restrict__ kv, float* __restrict__ ctx){
    __shared__ float kt[32][65];
    __shared__ float vt[32][65];
    int b = blockIdx.x >> 3, h = blockIdx.x & 7;
    int t = threadIdx.x;
    const bf16* kbase = kv + ((size_t)b*512 +       h*DH)*NSP;
    const bf16* vbase = kv + ((size_t)b*512 + 256 + h*DH)*NSP;
    int d = t & 31, e0 = (t>>5)*4;
    int sr = t>>3, sn = (t&7)*8;
    float a0=0.f, a1=0.f, a2=0.f, a3=0.f;
    for (int n0=0; n0<NSP; n0+=64){
        __syncthreads();
        bf16x8 k8 = *(const bf16x8*)(kbase + (size_t)sr*NSP + n0 + sn);
        bf16x8 v8 = *(const bf16x8*)(vbase + (size_t)sr*NSP + n0 + sn);
        #pragma unroll
        for (int j=0;j<8;j++){ kt[sr][sn+j] = bf2f(k8[j]); vt[sr][sn+j] = bf2f(v8[j]); }
        __syncthreads();
        #pragma unroll 8
        for (int j=0;j<64;j++){
            float kvv = kt[d][j];
            a0 += kvv * vt[e0+0][j];
            a1 += kvv * vt[e0+1][j];
            a2 += kvv * vt[e0+2][j];
            a3 += kvv * vt[e0+3][j];
        }
    }
    float* cb = ctx + (size_t)(b*8+h)*32*32;
    cb[d*32 + e0+0] = a0; cb[d*32 + e0+1] = a1;
    cb[d*32 + e0+2] = a2; cb[d*32 + e0+3] = a3;
}

// ---------------- K5: W2[b][o][h*32+e] = sum_d w_out[o][h*32+d] * ctx[b][h][d][e] ----------------
__global__ void k_merge(const float* __restrict__ w_out, const float* __restrict__ ctx,
                        bf16* __restrict__ W2){
    __shared__ float ctxs[NHEADS][32][32];
    int b = blockIdx.x;
    int t = threadIdx.x;
    const float* cb = ctx + (size_t)b*8192;
    #pragma unroll
    for (int i=0;i<32;i++) ((float*)ctxs)[i*256 + t] = cb[i*256 + t];
    __syncthreads();
    int o = t;
    const float* wrow = w_out + (size_t)o*CDIM;
    bf16* dst = W2 + ((size_t)b*CDIM + o)*CDIM;
    for (int h=0; h<8; h++){
        float wv[32];
        #pragma unroll
        for (int d=0; d<32; d++) wv[d] = wrow[h*32+d];
        for (int e=0; e<32; e++){
            float s = 0.f;
            #pragma unroll
            for (int d=0; d<32; d++) s += wv[d]*ctxs[h][d][e];
            dst[h*32+e] = f2bf(s);
        }
    }
}

// ---------------- K6: y = W2[b] @ q~T + b_out, then LayerNorm over channels; fp32 out ----------------
__global__ __launch_bounds__(256) void k_out_ln(const bf16* __restrict__ W2,
                                                const bf16* __restrict__ qT,
                                                const float* __restrict__ bout,
                                                const float* __restrict__ gamma,
                                                const float* __restrict__ beta,
                                                float* __restrict__ out){
    __shared__ union {
        struct { bf16 As[256*LDT]; bf16 Bs[64*LDT]; } s;
        float Y[256*66];
    } sm;
    __shared__ float red[2][4][64];
    __shared__ float mu_s[64], rstd_s[64];
    int b  = blockIdx.x >> 6;
    int n0 = (blockIdx.x & 63) * 64;
    int t = threadIdx.x, wv = t>>6, lane = t&63;
    f32x4 acc[4][4];
    #pragma unroll
    for (int i=0;i<16;i++) ((f32x4*)acc)[i] = (f32x4){0.f,0.f,0.f,0.f};
    const bf16* Ab = W2 + (size_t)b*CDIM*CDIM;
    const bf16* Bb = qT + ((size_t)b*NSP + n0)*CDIM;
    for (int k0=0; k0<CDIM; k0+=32){
        __syncthreads();
        #pragma unroll
        for (int i=0;i<4;i++){
            int lin = i*256 + t; int r = lin>>2; int c8 = (lin&3)*8;
            *(bf16x8*)&sm.s.As[r*LDT + c8] = *(const bf16x8*)(Ab + (size_t)r*CDIM + k0 + c8);
        }
        { int r = t>>2; int c8 = (t&3)*8;
          *(bf16x8*)&sm.s.Bs[r*LDT + c8] = *(const bf16x8*)(Bb + (size_t)r*CDIM + k0 + c8); }
        __syncthreads();
        bf16x8 af[4], bfr[4];
        #pragma unroll
        for (int mi=0;mi<4;mi++)
            af[mi] = *(const bf16x8*)&sm.s.As[(wv*64 + mi*16 + (lane&15))*LDT + (lane>>4)*8];
        #pragma unroll
        for (int ni=0;ni<4;ni++)
            bfr[ni] = *(const bf16x8*)&sm.s.Bs[(ni*16 + (lane&15))*LDT + (lane>>4)*8];
        #pragma unroll
        for (int mi=0;mi<4;mi++)
            #pragma unroll
            for (int ni=0;ni<4;ni++)
                acc[mi][ni] = __builtin_amdgcn_mfma_f32_16x16x32_bf16(af[mi], bfr[ni], acc[mi][ni], 0, 0, 0);
    }
    __syncthreads();   // done reading As/Bs; safe to overlay Y
    #pragma unroll
    for (int mi=0;mi<4;mi++)
        #pragma unroll
        for (int ni=0;ni<4;ni++)
            #pragma unroll
            for (int r=0;r<4;r++){
                int o = wv*64 + mi*16 + (lane>>4)*4 + r;
                int n = ni*16 + (lane&15);
                sm.Y[o*66 + n] = acc[mi][ni][r];
            }
    __syncthreads();
    int n = t & 63, q = t >> 6;
    float s = 0.f, s2 = 0.f;
    for (int o=64*q; o<64*q+64; o++){
        float y = sm.Y[o*66+n] + bout[o];
        s += y; s2 += y*y;
    }
    red[0][q][n] = s; red[1][q][n] = s2;
    __syncthreads();
    if (t < 64){
        float S  = red[0][0][t]+red[0][1][t]+red[0][2][t]+red[0][3][t];
        float S2 = red[1][0][t]+red[1][1][t]+red[1][2][t]+red[1][3][t];
        float mu = S * (1.f/256.f);
        float var = S2*(1.f/256.f) - mu*mu;
        mu_s[t] = mu; rstd_s[t] = rsqrtf(var + 1e-5f);
    }
    __syncthreads();
    float mu = mu_s[n], rstd = rstd_s[n];
    size_t ob = (size_t)b*CDIM*NSP + n0 + n;
    for (int o=64*q; o<64*q+64; o++){
        float y = sm.Y[o*66+n] + bout[o];
        out[ob + (size_t)o*NSP] = (y - mu)*rstd*gamma[o] + beta[o];
    }
}

extern "C" void kernel_launch(void* const* d_in, const int* in_sizes, int n_in,
                              void* d_out, int out_size, void* d_ws, size_t ws_size,
                              hipStream_t stream){
    const float* x     = (const float*)d_in[0];
    const float* w_qkv = (const float*)d_in[1];
    const float* w_out = (const float*)d_in[2];
    const float* b_out = (const float*)d_in[3];
    const float* gamma = (const float*)d_in[4];
    const float* beta  = (const float*)d_in[5];
    float* out = (float*)d_out;
    char* ws = (char*)d_ws;
    // ws layout (bytes):
    //   xT  bf16 [16][4096][256] : 0          .. 33,554,432
    //   qT  bf16 [16][4096][256] : 33,554,432 .. 67,108,864
    //   kv  bf16 [16][512][4096] : 67,108,864 .. 134,217,728
    //   ctx f32  [16][8][32][32] : 134,217,728 .. 134,742,016
    //   W2  bf16 [16][256][256]  : 134,742,016 .. 136,839,168   (~130.5 MB total)
    bf16*  xT  = (bf16*) ws;
    bf16*  qT  = (bf16*)(ws + 33554432ull);
    bf16*  kv  = (bf16*)(ws + 67108864ull);
    float* ctx = (float*)(ws + 134217728ull);
    bf16*  W2  = (bf16*)(ws + 134742016ull);

    k_transpose<<<dim3(64, 4, NB), 256, 0, stream>>>(x, xT);
    k_qkv      <<<dim3(6, 32*NB),  256, 0, stream>>>(w_qkv, xT, qT, kv);
    k_qsoftmax <<<dim3(NB*NSP/32), 256, 0, stream>>>(qT);
    k_ksoftmax <<<dim3(NB*256*64/4), 256, 0, stream>>>(kv);
    k_context  <<<dim3(NB*8),      256, 0, stream>>>(kv, ctx);
    k_merge    <<<dim3(NB),        256, 0, stream>>>(w_out, ctx, W2);
    k_out_ln   <<<dim3(NB*64),     256, 0, stream>>>(W2, qT, b_out, gamma, beta, out);
}

// Round 4
// 311.205 us; speedup vs baseline: 1.5085x; 1.5085x over previous
//
#include <hip/hip_runtime.h>
#include <hip/hip_bf16.h>

#define NB 16
#define CDIM 256
#define NHEADS 8
#define DH 32
#define NSP 4096
#define O3 768

typedef __bf16 bf16;
typedef bf16 bf16x4 __attribute__((ext_vector_type(4)));
typedef bf16 bf16x8 __attribute__((ext_vector_type(8)));
typedef float f32x4 __attribute__((ext_vector_type(4)));
typedef float f32x16 __attribute__((ext_vector_type(16)));

static __device__ __forceinline__ float bf2f(bf16 x){ return (float)x; }
static __device__ __forceinline__ bf16 f2bf(float x){ return (bf16)x; }

// ---------------- K0: transpose+convert x[b][c][n] (fp32) -> xT[b][n][c] (bf16) ----------------
__global__ void k_transpose(const float* __restrict__ x, bf16* __restrict__ xT){
    __shared__ bf16 tile[64][72];
    int b = blockIdx.z;
    int c0 = blockIdx.y * 64;
    int n0 = blockIdx.x * 64;
    int t = threadIdx.x;
    const float* xb = x + (size_t)b * CDIM * NSP;
    #pragma unroll
    for (int i = 0; i < 4; ++i){
        int lin = i*256 + t;
        int c = lin >> 4;           // 0..63
        int n4 = (lin & 15) * 4;    // 0..60
        f32x4 f = *(const f32x4*)(xb + (size_t)(c0 + c)*NSP + n0 + n4);
        bf16x4 v4;
        #pragma unroll
        for (int j = 0; j < 4; ++j) v4[j] = f2bf(f[j]);
        *(bf16x4*)&tile[c][n4] = v4;
    }
    __syncthreads();
    bf16* xTb = xT + (size_t)b * NSP * CDIM;
    #pragma unroll
    for (int i = 0; i < 2; ++i){
        int lin = i*256 + t;
        int n = lin >> 3;           // 0..63
        int c8 = (lin & 7) * 8;     // 0..56
        bf16x8 v;
        #pragma unroll
        for (int j = 0; j < 8; ++j) v[j] = tile[c8+j][n];
        *(bf16x8*)(xTb + (size_t)(n0+n)*CDIM + c0 + c8) = v;
    }
}

// ---------------- K1: qkv GEMM  (M=768, K=256, N=4096 per batch) ----------------
#define LDT 40   // padded LDS row stride in bf16 (80B, 16B-aligned)
__global__ __launch_bounds__(256) void k_qkv(const float* __restrict__ w,
                                             const bf16* __restrict__ xT,
                                             bf16* __restrict__ qT,
                                             bf16* __restrict__ kv){
    __shared__ bf16 As[128*LDT];
    __shared__ bf16 Bs[128*LDT];
    int m0 = blockIdx.x * 128;           // 6 tiles over 768
    int b  = blockIdx.y >> 5;            // 32 n-tiles per batch
    int n0 = (blockIdx.y & 31) * 128;
    int t = threadIdx.x;
    int wv = t >> 6, lane = t & 63;
    f32x4 acc[2][8];
    #pragma unroll
    for (int i=0;i<16;i++) ((f32x4*)acc)[i] = (f32x4){0.f,0.f,0.f,0.f};

    const bf16* xb = xT + ((size_t)b*NSP + n0)*CDIM;
    for (int k0 = 0; k0 < CDIM; k0 += 32){
        __syncthreads();
        #pragma unroll
        for (int i=0;i<2;i++){
            int lin = i*256 + t; int r = lin>>2; int c8 = (lin&3)*8;
            const float* wp = w + (size_t)(m0+r)*CDIM + k0 + c8;
            f32x4 a0 = *(const f32x4*)wp;
            f32x4 a1 = *(const f32x4*)(wp + 4);
            bf16x8 av;
            #pragma unroll
            for (int j=0;j<4;j++){ av[j] = f2bf(a0[j]); av[4+j] = f2bf(a1[j]); }
            *(bf16x8*)&As[r*LDT + c8] = av;
            *(bf16x8*)&Bs[r*LDT + c8] = *(const bf16x8*)(xb + (size_t)r*CDIM + k0 + c8);
        }
        __syncthreads();
        bf16x8 af[2], bfr[8];
        #pragma unroll
        for (int mi=0; mi<2; mi++)
            af[mi] = *(const bf16x8*)&As[(wv*32 + mi*16 + (lane&15))*LDT + (lane>>4)*8];
        #pragma unroll
        for (int ni=0; ni<8; ni++)
            bfr[ni] = *(const bf16x8*)&Bs[(ni*16 + (lane&15))*LDT + (lane>>4)*8];
        #pragma unroll
        for (int mi=0; mi<2; mi++)
            #pragma unroll
            for (int ni=0; ni<8; ni++)
                acc[mi][ni] = __builtin_amdgcn_mfma_f32_16x16x32_bf16(af[mi], bfr[ni], acc[mi][ni], 0, 0, 0);
    }
    if (m0 < 256){
        bf16* qTb = qT + (size_t)b * NSP * CDIM;
        #pragma unroll
        for (int mi=0;mi<2;mi++){
            #pragma unroll
            for (int ni=0;ni<8;ni++){
                int n = n0 + ni*16 + (lane&15);
                int o = m0 + wv*32 + mi*16 + (lane>>4)*4;
                bf16x4 v4;
                #pragma unroll
                for (int r=0;r<4;r++) v4[r] = f2bf(acc[mi][ni][r]);
                *(bf16x4*)(qTb + (size_t)n*CDIM + o) = v4;
            }
        }
    } else {
        bf16* kvb = kv + (size_t)b * 512 * NSP;
        int c0t = m0 - 256;
        #pragma unroll
        for (int mi=0;mi<2;mi++){
            #pragma unroll
            for (int ni=0;ni<8;ni++){
                int col = n0 + ni*16 + (lane&15);
                #pragma unroll
                for (int r=0;r<4;r++){
                    int c = c0t + wv*32 + mi*16 + (lane>>4)*4 + r;
                    kvb[(size_t)c*NSP + col] = f2bf(acc[mi][ni][r]);
                }
            }
        }
    }
}

// ---------------- K2: q softmax over d (32 contiguous channels), in-place on qT ----------------
__global__ void k_qsoftmax(bf16* __restrict__ qT){
    int t = threadIdx.x;
    size_t row = (size_t)blockIdx.x*32 + (t>>3);
    bf16* p = qT + row*CDIM + (size_t)(t&7)*DH;
    float v[32]; float mx = -1e30f;
    #pragma unroll
    for (int g=0; g<4; g++){
        bf16x8 i8 = *(const bf16x8*)(p + g*8);
        #pragma unroll
        for (int j=0;j<8;j++){ v[g*8+j] = bf2f(i8[j]); mx = fmaxf(mx, v[g*8+j]); }
    }
    float s = 0.f;
    #pragma unroll
    for (int d=0; d<32; d++){ v[d] = __expf(v[d]-mx); s += v[d]; }
    float inv = 1.f/s;
    #pragma unroll
    for (int g=0; g<4; g++){
        bf16x8 o8;
        #pragma unroll
        for (int j=0;j<8;j++) o8[j] = f2bf(v[g*8+j]*inv);
        *(bf16x8*)(p + g*8) = o8;
    }
}

// ---------------- K3: k softmax over w (in-place on kv k-section) ----------------
__global__ void k_ksoftmax(bf16* __restrict__ kv){
    int gid = blockIdx.x*4 + (threadIdx.x>>6);
    int lane = threadIdx.x & 63;
    int b = gid >> 14;
    int rem = gid & 16383;
    int c = rem >> 6;
    int hrow = rem & 63;
    bf16* p = kv + ((size_t)b*512 + c)*NSP + hrow*64 + lane;
    float v = bf2f(*p);
    float m = v;
    #pragma unroll
    for (int off=32; off; off>>=1) m = fmaxf(m, __shfl_xor(m, off, 64));
    float e = __expf(v - m);
    float s = e;
    #pragma unroll
    for (int off=32; off; off>>=1) s += __shfl_xor(s, off, 64);
    *p = f2bf(e/s);
}

// ---------------- K4: ctx partials via MFMA 32x32x16, split-K 16-way ----------------
// ctx[b,h,d,e] = sum_n k~[d,n] * v[e,n]. A=k (M=d), B=v (N=e), contraction n.
// A-frag: k[lane&31][n0 + (lane>>5)*8 + j]  (contiguous bf16x8 global load)
// B-frag: v[lane&31][n0 + (lane>>5)*8 + j]  (same addressing)
// Each wave: 256 n -> 16 MFMA. Partial p = chunk*4+wave in [0,16).
__global__ __launch_bounds__(256) void k_context(const bf16* __restrict__ kv,
                                                 float* __restrict__ ctx_p){
    int blk = blockIdx.x;            // bh*4 + chunk
    int bh = blk >> 2;
    int chunk = blk & 3;
    int b = bh >> 3, h = bh & 7;
    int wave = threadIdx.x >> 6, lane = threadIdx.x & 63;
    int nbase = chunk*1024 + wave*256;
    int row = lane & 31;
    int koff = (lane >> 5) * 8;
    const bf16* kp = kv + ((size_t)b*512 +       h*DH + row)*NSP + nbase + koff;
    const bf16* vp = kv + ((size_t)b*512 + 256 + h*DH + row)*NSP + nbase + koff;
    f32x16 acc;
    #pragma unroll
    for (int i=0;i<16;i++) acc[i] = 0.f;
    #pragma unroll
    for (int s=0; s<16; s++){
        bf16x8 a  = *(const bf16x8*)(kp + s*16);
        bf16x8 bb = *(const bf16x8*)(vp + s*16);
        acc = __builtin_amdgcn_mfma_f32_32x32x16_bf16(a, bb, acc, 0, 0, 0);
    }
    float* dst = ctx_p + ((size_t)bh*16 + chunk*4 + wave)*1024;
    #pragma unroll
    for (int r=0;r<16;r++){
        int d = (r&3) + 8*(r>>2) + 4*(lane>>5);
        dst[d*32 + (lane&31)] = acc[r];
    }
}

// ---------------- K5: reduce partials + W2[b][o][h*32+e] = sum_d w_out[o][h*32+d]*ctx[d][e] ----------------
__global__ void k_merge(const float* __restrict__ w_out, const float* __restrict__ ctx_p,
                        bf16* __restrict__ W2){
    __shared__ float ctxs[32][32];
    int bh = blockIdx.x;
    int b = bh >> 3, h = bh & 7;
    int t = threadIdx.x;
    const float* base = ctx_p + (size_t)bh*16*1024;
    #pragma unroll
    for (int i=0;i<4;i++){
        int idx = i*256 + t;
        float s = 0.f;
        #pragma unroll
        for (int p=0;p<16;p++) s += base[p*1024 + idx];
        ((float*)ctxs)[idx] = s;
    }
    __syncthreads();
    int o = t;
    const float* wrow = w_out + (size_t)o*CDIM + h*DH;
    float wv[32];
    #pragma unroll
    for (int d=0;d<32;d++) wv[d] = wrow[d];
    bf16* dst = W2 + ((size_t)b*CDIM + o)*CDIM + h*DH;
    #pragma unroll
    for (int g=0;g<4;g++){
        bf16x8 o8;
        #pragma unroll
        for (int jj=0;jj<8;jj++){
            int e = g*8 + jj;
            float s = 0.f;
            #pragma unroll
            for (int d=0;d<32;d++) s += wv[d]*ctxs[d][e];
            o8[jj] = f2bf(s);
        }
        *(bf16x8*)(dst + g*8) = o8;
    }
}

// ---------------- K6: y = W2[b] @ q~T + b_out, then LayerNorm over channels; fp32 out ----------------
__global__ __launch_bounds__(256) void k_out_ln(const bf16* __restrict__ W2,
                                                const bf16* __restrict__ qT,
                                                const float* __restrict__ bout,
                                                const float* __restrict__ gamma,
                                                const float* __restrict__ beta,
                                                float* __restrict__ out){
    __shared__ union {
        struct { bf16 As[256*LDT]; bf16 Bs[64*LDT]; } s;
        float Y[256*66];
    } sm;
    __shared__ float red[2][4][64];
    __shared__ float mu_s[64], rstd_s[64];
    int b  = blockIdx.x >> 6;
    int n0 = (blockIdx.x & 63) * 64;
    int t = threadIdx.x, wv = t>>6, lane = t&63;
    f32x4 acc[4][4];
    #pragma unroll
    for (int i=0;i<16;i++) ((f32x4*)acc)[i] = (f32x4){0.f,0.f,0.f,0.f};
    const bf16* Ab = W2 + (size_t)b*CDIM*CDIM;
    const bf16* Bb = qT + ((size_t)b*NSP + n0)*CDIM;
    for (int k0=0; k0<CDIM; k0+=32){
        __syncthreads();
        #pragma unroll
        for (int i=0;i<4;i++){
            int lin = i*256 + t; int r = lin>>2; int c8 = (lin&3)*8;
            *(bf16x8*)&sm.s.As[r*LDT + c8] = *(const bf16x8*)(Ab + (size_t)r*CDIM + k0 + c8);
        }
        { int r = t>>2; int c8 = (t&3)*8;
          *(bf16x8*)&sm.s.Bs[r*LDT + c8] = *(const bf16x8*)(Bb + (size_t)r*CDIM + k0 + c8); }
        __syncthreads();
        bf16x8 af[4], bfr[4];
        #pragma unroll
        for (int mi=0;mi<4;mi++)
            af[mi] = *(const bf16x8*)&sm.s.As[(wv*64 + mi*16 + (lane&15))*LDT + (lane>>4)*8];
        #pragma unroll
        for (int ni=0;ni<4;ni++)
            bfr[ni] = *(const bf16x8*)&sm.s.Bs[(ni*16 + (lane&15))*LDT + (lane>>4)*8];
        #pragma unroll
        for (int mi=0;mi<4;mi++)
            #pragma unroll
            for (int ni=0;ni<4;ni++)
                acc[mi][ni] = __builtin_amdgcn_mfma_f32_16x16x32_bf16(af[mi], bfr[ni], acc[mi][ni], 0, 0, 0);
    }
    __syncthreads();
    #pragma unroll
    for (int mi=0;mi<4;mi++)
        #pragma unroll
        for (int ni=0;ni<4;ni++)
            #pragma unroll
            for (int r=0;r<4;r++){
                int o = wv*64 + mi*16 + (lane>>4)*4 + r;
                int n = ni*16 + (lane&15);
                sm.Y[o*66 + n] = acc[mi][ni][r];
            }
    __syncthreads();
    int n = t & 63, q = t >> 6;
    float s = 0.f, s2 = 0.f;
    for (int o=64*q; o<64*q+64; o++){
        float y = sm.Y[o*66+n] + bout[o];
        s += y; s2 += y*y;
    }
    red[0][q][n] = s; red[1][q][n] = s2;
    __syncthreads();
    if (t < 64){
        float S  = red[0][0][t]+red[0][1][t]+red[0][2][t]+red[0][3][t];
        float S2 = red[1][0][t]+red[1][1][t]+red[1][2][t]+red[1][3][t];
        float mu = S * (1.f/256.f);
        float var = S2*(1.f/256.f) - mu*mu;
        mu_s[t] = mu; rstd_s[t] = rsqrtf(var + 1e-5f);
    }
    __syncthreads();
    float mu = mu_s[n], rstd = rstd_s[n];
    size_t ob = (size_t)b*CDIM*NSP + n0 + n;
    for (int o=64*q; o<64*q+64; o++){
        float y = sm.Y[o*66+n] + bout[o];
        out[ob + (size_t)o*NSP] = (y - mu)*rstd*gamma[o] + beta[o];
    }
}

extern "C" void kernel_launch(void* const* d_in, const int* in_sizes, int n_in,
                              void* d_out, int out_size, void* d_ws, size_t ws_size,
                              hipStream_t stream){
    const float* x     = (const float*)d_in[0];
    const float* w_qkv = (const float*)d_in[1];
    const float* w_out = (const float*)d_in[2];
    const float* b_out = (const float*)d_in[3];
    const float* gamma = (const float*)d_in[4];
    const float* beta  = (const float*)d_in[5];
    float* out = (float*)d_out;
    char* ws = (char*)d_ws;
    // ws layout (bytes):
    //   xT    bf16 [16][4096][256] : 0          .. 33,554,432   (dead after k_qkv)
    //   ctx_p f32  [128][16][1024] : 0          .. 8,388,608    (overlaps dead xT)
    //   qT    bf16 [16][4096][256] : 33,554,432 .. 67,108,864
    //   kv    bf16 [16][512][4096] : 67,108,864 .. 134,217,728
    //   W2    bf16 [16][256][256]  : 134,742,016 .. 136,839,168
    bf16*  xT    = (bf16*) ws;
    float* ctx_p = (float*)ws;
    bf16*  qT    = (bf16*)(ws + 33554432ull);
    bf16*  kv    = (bf16*)(ws + 67108864ull);
    bf16*  W2    = (bf16*)(ws + 134742016ull);

    k_transpose<<<dim3(64, 4, NB), 256, 0, stream>>>(x, xT);
    k_qkv      <<<dim3(6, 32*NB),  256, 0, stream>>>(w_qkv, xT, qT, kv);
    k_qsoftmax <<<dim3(NB*NSP/32), 256, 0, stream>>>(qT);
    k_ksoftmax <<<dim3(NB*256*64/4), 256, 0, stream>>>(kv);
    k_context  <<<dim3(512),       256, 0, stream>>>(kv, ctx_p);
    k_merge    <<<dim3(128),       256, 0, stream>>>(w_out, ctx_p, W2);
    k_out_ln   <<<dim3(NB*64),     256, 0, stream>>>(W2, qT, b_out, gamma, beta, out);
}

// Round 5
// 271.482 us; speedup vs baseline: 1.7293x; 1.1463x over previous
//
#include <hip/hip_runtime.h>
#include <hip/hip_bf16.h>

#define NB 16
#define CDIM 256
#define NHEADS 8
#define DH 32
#define NSP 4096
#define O3 768

typedef __bf16 bf16;
typedef bf16 bf16x4 __attribute__((ext_vector_type(4)));
typedef bf16 bf16x8 __attribute__((ext_vector_type(8)));
typedef float f32x4 __attribute__((ext_vector_type(4)));
typedef float f32x16 __attribute__((ext_vector_type(16)));

static __device__ __forceinline__ float bf2f(bf16 x){ return (float)x; }
static __device__ __forceinline__ bf16 f2bf(float x){ return (bf16)x; }

// ---------------- K0: transpose+convert x[b][c][n] (fp32) -> xT[b][n][c] (bf16) ----------------
__global__ void k_transpose(const float* __restrict__ x, bf16* __restrict__ xT){
    __shared__ bf16 tile[64][72];
    int b = blockIdx.z;
    int c0 = blockIdx.y * 64;
    int n0 = blockIdx.x * 64;
    int t = threadIdx.x;
    const float* xb = x + (size_t)b * CDIM * NSP;
    #pragma unroll
    for (int i = 0; i < 4; ++i){
        int lin = i*256 + t;
        int c = lin >> 4;           // 0..63
        int n4 = (lin & 15) * 4;    // 0..60
        f32x4 f = *(const f32x4*)(xb + (size_t)(c0 + c)*NSP + n0 + n4);
        bf16x4 v4;
        #pragma unroll
        for (int j = 0; j < 4; ++j) v4[j] = f2bf(f[j]);
        *(bf16x4*)&tile[c][n4] = v4;
    }
    __syncthreads();
    bf16* xTb = xT + (size_t)b * NSP * CDIM;
    #pragma unroll
    for (int i = 0; i < 2; ++i){
        int lin = i*256 + t;
        int n = lin >> 3;           // 0..63
        int c8 = (lin & 7) * 8;     // 0..56
        bf16x8 v;
        #pragma unroll
        for (int j = 0; j < 8; ++j) v[j] = tile[c8+j][n];
        *(bf16x8*)(xTb + (size_t)(n0+n)*CDIM + c0 + c8) = v;
    }
}

// ---------------- K1: qkv GEMM + fused q/k softmax epilogues ----------------
// XCD-swizzled grid: bid = xcd + 8*slot; slot -> (m-tile, n-tile) with the 6
// m-tiles of one n-tile on consecutive slots (same XCD) for B-tile L2 reuse.
#define LDT 40   // padded LDS row stride in bf16 (80B, 16B-aligned)
__global__ __launch_bounds__(256) void k_qkv(const float* __restrict__ w,
                                             const bf16* __restrict__ xT,
                                             bf16* __restrict__ qT,
                                             bf16* __restrict__ kv){
    __shared__ bf16 As[128*LDT];
    __shared__ bf16 Bs[128*LDT];
    int bid = blockIdx.x;
    int xcd = bid & 7, slot = bid >> 3;      // 384 slots per xcd-residue
    int m  = slot % 6;
    int ntile = xcd*64 + slot/6;             // 0..511
    int b  = ntile >> 5;
    int n0 = (ntile & 31) * 128;
    int m0 = m * 128;
    int t = threadIdx.x;
    int wv = t >> 6, lane = t & 63;
    f32x4 acc[2][8];
    #pragma unroll
    for (int i=0;i<16;i++) ((f32x4*)acc)[i] = (f32x4){0.f,0.f,0.f,0.f};

    const bf16* xb = xT + ((size_t)b*NSP + n0)*CDIM;
    for (int k0 = 0; k0 < CDIM; k0 += 32){
        __syncthreads();
        #pragma unroll
        for (int i=0;i<2;i++){
            int lin = i*256 + t; int r = lin>>2; int c8 = (lin&3)*8;
            const float* wp = w + (size_t)(m0+r)*CDIM + k0 + c8;
            f32x4 a0 = *(const f32x4*)wp;
            f32x4 a1 = *(const f32x4*)(wp + 4);
            bf16x8 av;
            #pragma unroll
            for (int j=0;j<4;j++){ av[j] = f2bf(a0[j]); av[4+j] = f2bf(a1[j]); }
            *(bf16x8*)&As[r*LDT + c8] = av;
            *(bf16x8*)&Bs[r*LDT + c8] = *(const bf16x8*)(xb + (size_t)r*CDIM + k0 + c8);
        }
        __syncthreads();
        bf16x8 af[2], bfr[8];
        #pragma unroll
        for (int mi=0; mi<2; mi++)
            af[mi] = *(const bf16x8*)&As[(wv*32 + mi*16 + (lane&15))*LDT + (lane>>4)*8];
        #pragma unroll
        for (int ni=0; ni<8; ni++)
            bfr[ni] = *(const bf16x8*)&Bs[(ni*16 + (lane&15))*LDT + (lane>>4)*8];
        #pragma unroll
        for (int mi=0; mi<2; mi++)
            #pragma unroll
            for (int ni=0; ni<8; ni++)
                acc[mi][ni] = __builtin_amdgcn_mfma_f32_16x16x32_bf16(af[mi], bfr[ni], acc[mi][ni], 0, 0, 0);
    }
    if (m0 < 256){
        // ---- fused q softmax over d: wave's 32 rows == one head; combine lanes xor 16,32 ----
        #pragma unroll
        for (int ni=0;ni<8;ni++){
            float mx = -1e30f;
            #pragma unroll
            for (int mi=0;mi<2;mi++)
                #pragma unroll
                for (int r=0;r<4;r++) mx = fmaxf(mx, acc[mi][ni][r]);
            mx = fmaxf(mx, __shfl_xor(mx, 16, 64));
            mx = fmaxf(mx, __shfl_xor(mx, 32, 64));
            float s = 0.f;
            #pragma unroll
            for (int mi=0;mi<2;mi++)
                #pragma unroll
                for (int r=0;r<4;r++){
                    float e = __expf(acc[mi][ni][r] - mx);
                    acc[mi][ni][r] = e; s += e;
                }
            s += __shfl_xor(s, 16, 64);
            s += __shfl_xor(s, 32, 64);
            float inv = 1.f/s;
            #pragma unroll
            for (int mi=0;mi<2;mi++)
                #pragma unroll
                for (int r=0;r<4;r++) acc[mi][ni][r] *= inv;
        }
        bf16* qTb = qT + (size_t)b * NSP * CDIM;
        #pragma unroll
        for (int mi=0;mi<2;mi++){
            #pragma unroll
            for (int ni=0;ni<8;ni++){
                int n = n0 + ni*16 + (lane&15);
                int o = m0 + wv*32 + mi*16 + (lane>>4)*4;
                bf16x4 v4;
                #pragma unroll
                for (int r=0;r<4;r++) v4[r] = f2bf(acc[mi][ni][r]);
                *(bf16x4*)(qTb + (size_t)n*CDIM + o) = v4;
            }
        }
    } else {
        if (m0 < 512){
            // ---- fused k softmax over w: each 64-col group = ni 0..3 / 4..7 x 16 lanes ----
            #pragma unroll
            for (int mi=0;mi<2;mi++)
                #pragma unroll
                for (int r=0;r<4;r++)
                    #pragma unroll
                    for (int grp=0;grp<2;grp++){
                        float mx = -1e30f;
                        #pragma unroll
                        for (int q=0;q<4;q++) mx = fmaxf(mx, acc[mi][grp*4+q][r]);
                        #pragma unroll
                        for (int msk=1; msk<16; msk<<=1) mx = fmaxf(mx, __shfl_xor(mx, msk, 64));
                        float s = 0.f;
                        #pragma unroll
                        for (int q=0;q<4;q++){
                            float e = __expf(acc[mi][grp*4+q][r] - mx);
                            acc[mi][grp*4+q][r] = e; s += e;
                        }
                        #pragma unroll
                        for (int msk=1; msk<16; msk<<=1) s += __shfl_xor(s, msk, 64);
                        float inv = 1.f/s;
                        #pragma unroll
                        for (int q=0;q<4;q++) acc[mi][grp*4+q][r] *= inv;
                    }
        }
        bf16* kvb = kv + (size_t)b * 512 * NSP;
        int c0t = m0 - 256;
        #pragma unroll
        for (int mi=0;mi<2;mi++){
            #pragma unroll
            for (int ni=0;ni<8;ni++){
                int col = n0 + ni*16 + (lane&15);
                #pragma unroll
                for (int r=0;r<4;r++){
                    int c = c0t + wv*32 + mi*16 + (lane>>4)*4 + r;
                    kvb[(size_t)c*NSP + col] = f2bf(acc[mi][ni][r]);
                }
            }
        }
    }
}

// ---------------- K4: ctx partials via MFMA 32x32x16, split-K 16-way ----------------
__global__ __launch_bounds__(256) void k_context(const bf16* __restrict__ kv,
                                                 float* __restrict__ ctx_p){
    int blk = blockIdx.x;            // bh*4 + chunk
    int bh = blk >> 2;
    int chunk = blk & 3;
    int b = bh >> 3, h = bh & 7;
    int wave = threadIdx.x >> 6, lane = threadIdx.x & 63;
    int nbase = chunk*1024 + wave*256;
    int row = lane & 31;
    int koff = (lane >> 5) * 8;
    const bf16* kp = kv + ((size_t)b*512 +       h*DH + row)*NSP + nbase + koff;
    const bf16* vp = kv + ((size_t)b*512 + 256 + h*DH + row)*NSP + nbase + koff;
    f32x16 acc;
    #pragma unroll
    for (int i=0;i<16;i++) acc[i] = 0.f;
    #pragma unroll
    for (int s=0; s<16; s++){
        bf16x8 a  = *(const bf16x8*)(kp + s*16);
        bf16x8 bb = *(const bf16x8*)(vp + s*16);
        acc = __builtin_amdgcn_mfma_f32_32x32x16_bf16(a, bb, acc, 0, 0, 0);
    }
    float* dst = ctx_p + ((size_t)bh*16 + chunk*4 + wave)*1024;
    #pragma unroll
    for (int r=0;r<16;r++){
        int d = (r&3) + 8*(r>>2) + 4*(lane>>5);
        dst[d*32 + (lane&31)] = acc[r];
    }
}

// ---------------- K5: reduce partials + W2 = w_out x ctx (per b,h) ----------------
__global__ void k_merge(const float* __restrict__ w_out, const float* __restrict__ ctx_p,
                        bf16* __restrict__ W2){
    __shared__ float ctxs[32][32];
    int bh = blockIdx.x;
    int b = bh >> 3, h = bh & 7;
    int t = threadIdx.x;
    const float* base = ctx_p + (size_t)bh*16*1024;
    #pragma unroll
    for (int i=0;i<4;i++){
        int idx = i*256 + t;
        float s = 0.f;
        #pragma unroll
        for (int p=0;p<16;p++) s += base[p*1024 + idx];
        ((float*)ctxs)[idx] = s;
    }
    __syncthreads();
    int o = t;
    const float* wrow = w_out + (size_t)o*CDIM + h*DH;
    float wv[32];
    #pragma unroll
    for (int d=0;d<32;d++) wv[d] = wrow[d];
    bf16* dst = W2 + ((size_t)b*CDIM + o)*CDIM + h*DH;
    #pragma unroll
    for (int g=0;g<4;g++){
        bf16x8 o8;
        #pragma unroll
        for (int jj=0;jj<8;jj++){
            int e = g*8 + jj;
            float s = 0.f;
            #pragma unroll
            for (int d=0;d<32;d++) s += wv[d]*ctxs[d][e];
            o8[jj] = f2bf(s);
        }
        *(bf16x8*)(dst + g*8) = o8;
    }
}

// ---------------- K6: y = W2[b] @ q~T + b_out, then LayerNorm over channels; fp32 out ----------------
__global__ __launch_bounds__(256) void k_out_ln(const bf16* __restrict__ W2,
                                                const bf16* __restrict__ qT,
                                                const float* __restrict__ bout,
                                                const float* __restrict__ gamma,
                                                const float* __restrict__ beta,
                                                float* __restrict__ out){
    __shared__ union {
        struct { bf16 As[256*LDT]; bf16 Bs[64*LDT]; } s;
        float Y[256*66];
    } sm;
    __shared__ float red[2][4][64];
    __shared__ float mu_s[64], rstd_s[64];
    int b  = blockIdx.x >> 6;
    int n0 = (blockIdx.x & 63) * 64;
    int t = threadIdx.x, wv = t>>6, lane = t&63;
    f32x4 acc[4][4];
    #pragma unroll
    for (int i=0;i<16;i++) ((f32x4*)acc)[i] = (f32x4){0.f,0.f,0.f,0.f};
    const bf16* Ab = W2 + (size_t)b*CDIM*CDIM;
    const bf16* Bb = qT + ((size_t)b*NSP + n0)*CDIM;
    for (int k0=0; k0<CDIM; k0+=32){
        __syncthreads();
        #pragma unroll
        for (int i=0;i<4;i++){
            int lin = i*256 + t; int r = lin>>2; int c8 = (lin&3)*8;
            *(bf16x8*)&sm.s.As[r*LDT + c8] = *(const bf16x8*)(Ab + (size_t)r*CDIM + k0 + c8);
        }
        { int r = t>>2; int c8 = (t&3)*8;
          *(bf16x8*)&sm.s.Bs[r*LDT + c8] = *(const bf16x8*)(Bb + (size_t)r*CDIM + k0 + c8); }
        __syncthreads();
        bf16x8 af[4], bfr[4];
        #pragma unroll
        for (int mi=0;mi<4;mi++)
            af[mi] = *(const bf16x8*)&sm.s.As[(wv*64 + mi*16 + (lane&15))*LDT + (lane>>4)*8];
        #pragma unroll
        for (int ni=0;ni<4;ni++)
            bfr[ni] = *(const bf16x8*)&sm.s.Bs[(ni*16 + (lane&15))*LDT + (lane>>4)*8];
        #pragma unroll
        for (int mi=0;mi<4;mi++)
            #pragma unroll
            for (int ni=0;ni<4;ni++)
                acc[mi][ni] = __builtin_amdgcn_mfma_f32_16x16x32_bf16(af[mi], bfr[ni], acc[mi][ni], 0, 0, 0);
    }
    __syncthreads();
    #pragma unroll
    for (int mi=0;mi<4;mi++)
        #pragma unroll
        for (int ni=0;ni<4;ni++)
            #pragma unroll
            for (int r=0;r<4;r++){
                int o = wv*64 + mi*16 + (lane>>4)*4 + r;
                int n = ni*16 + (lane&15);
                sm.Y[o*66 + n] = acc[mi][ni][r];
            }
    __syncthreads();
    int n = t & 63, q = t >> 6;
    float s = 0.f, s2 = 0.f;
    for (int o=64*q; o<64*q+64; o++){
        float y = sm.Y[o*66+n] + bout[o];
        s += y; s2 += y*y;
    }
    red[0][q][n] = s; red[1][q][n] = s2;
    __syncthreads();
    if (t < 64){
        float S  = red[0][0][t]+red[0][1][t]+red[0][2][t]+red[0][3][t];
        float S2 = red[1][0][t]+red[1][1][t]+red[1][2][t]+red[1][3][t];
        float mu = S * (1.f/256.f);
        float var = S2*(1.f/256.f) - mu*mu;
        mu_s[t] = mu; rstd_s[t] = rsqrtf(var + 1e-5f);
    }
    __syncthreads();
    float mu = mu_s[n], rstd = rstd_s[n];
    size_t ob = (size_t)b*CDIM*NSP + n0 + n;
    for (int o=64*q; o<64*q+64; o++){
        float y = sm.Y[o*66+n] + bout[o];
        out[ob + (size_t)o*NSP] = (y - mu)*rstd*gamma[o] + beta[o];
    }
}

extern "C" void kernel_launch(void* const* d_in, const int* in_sizes, int n_in,
                              void* d_out, int out_size, void* d_ws, size_t ws_size,
                              hipStream_t stream){
    const float* x     = (const float*)d_in[0];
    const float* w_qkv = (const float*)d_in[1];
    const float* w_out = (const float*)d_in[2];
    const float* b_out = (const float*)d_in[3];
    const float* gamma = (const float*)d_in[4];
    const float* beta  = (const float*)d_in[5];
    float* out = (float*)d_out;
    char* ws = (char*)d_ws;
    // ws layout (bytes):
    //   xT    bf16 [16][4096][256] : 0          .. 33,554,432   (dead after k_qkv)
    //   ctx_p f32  [128][16][1024] : 0          .. 8,388,608    (overlaps dead xT)
    //   qT    bf16 [16][4096][256] : 33,554,432 .. 67,108,864
    //   kv    bf16 [16][512][4096] : 67,108,864 .. 134,217,728
    //   W2    bf16 [16][256][256]  : 134,742,016 .. 136,839,168
    bf16*  xT    = (bf16*) ws;
    float* ctx_p = (float*)ws;
    bf16*  qT    = (bf16*)(ws + 33554432ull);
    bf16*  kv    = (bf16*)(ws + 67108864ull);
    bf16*  W2    = (bf16*)(ws + 134742016ull);

    k_transpose<<<dim3(64, 4, NB), 256, 0, stream>>>(x, xT);
    k_qkv      <<<dim3(3072),      256, 0, stream>>>(w_qkv, xT, qT, kv);
    k_context  <<<dim3(512),       256, 0, stream>>>(kv, ctx_p);
    k_merge    <<<dim3(128),       256, 0, stream>>>(w_out, ctx_p, W2);
    k_out_ln   <<<dim3(NB*64),     256, 0, stream>>>(W2, qT, b_out, gamma, beta, out);
}

// Round 6
// 266.871 us; speedup vs baseline: 1.7591x; 1.0173x over previous
//
#include <hip/hip_runtime.h>
#include <hip/hip_bf16.h>

#define NB 16
#define CDIM 256
#define NHEADS 8
#define DH 32
#define NSP 4096
#define O3 768

typedef __bf16 bf16;
typedef bf16 bf16x4 __attribute__((ext_vector_type(4)));
typedef bf16 bf16x8 __attribute__((ext_vector_type(8)));
typedef float f32x4 __attribute__((ext_vector_type(4)));
typedef float f32x16 __attribute__((ext_vector_type(16)));

static __device__ __forceinline__ float bf2f(bf16 x){ return (float)x; }
static __device__ __forceinline__ bf16 f2bf(float x){ return (bf16)x; }

// async global->LDS, 16B per lane; lds dst must be wave-uniform base (lane*16 auto)
static __device__ __forceinline__ void gld16(const bf16* g, bf16* l){
    __builtin_amdgcn_global_load_lds((const __attribute__((address_space(1))) void*)g,
                                     (__attribute__((address_space(3))) void*)l, 16, 0, 0);
}

// ---------------- K0: transpose+convert x[b][c][n] (fp32) -> xT[b][n][c] (bf16) ----------------
__global__ void k_transpose(const float* __restrict__ x, bf16* __restrict__ xT){
    __shared__ bf16 tile[64][72];
    int b = blockIdx.z;
    int c0 = blockIdx.y * 64;
    int n0 = blockIdx.x * 64;
    int t = threadIdx.x;
    const float* xb = x + (size_t)b * CDIM * NSP;
    #pragma unroll
    for (int i = 0; i < 4; ++i){
        int lin = i*256 + t;
        int c = lin >> 4;
        int n4 = (lin & 15) * 4;
        f32x4 f = *(const f32x4*)(xb + (size_t)(c0 + c)*NSP + n0 + n4);
        bf16x4 v4;
        #pragma unroll
        for (int j = 0; j < 4; ++j) v4[j] = f2bf(f[j]);
        *(bf16x4*)&tile[c][n4] = v4;
    }
    __syncthreads();
    bf16* xTb = xT + (size_t)b * NSP * CDIM;
    #pragma unroll
    for (int i = 0; i < 2; ++i){
        int lin = i*256 + t;
        int n = lin >> 3;
        int c8 = (lin & 7) * 8;
        bf16x8 v;
        #pragma unroll
        for (int j = 0; j < 8; ++j) v[j] = tile[c8+j][n];
        *(bf16x8*)(xTb + (size_t)(n0+n)*CDIM + c0 + c8) = v;
    }
}

// ---------------- K0b: convert w_qkv fp32 -> bf16 ----------------
__global__ void k_wcvt(const float* __restrict__ w, bf16* __restrict__ w2){
    int idx = (blockIdx.x*256 + threadIdx.x) * 4;
    f32x4 f = *(const f32x4*)(w + idx);
    bf16x4 v;
    #pragma unroll
    for (int j=0;j<4;j++) v[j] = f2bf(f[j]);
    *(bf16x4*)(w2 + idx) = v;
}

// ---------------- K1: qkv GEMM + fused q/k softmax epilogues ----------------
// global_load_lds staging with XOR-swizzled segment order: slot(r,c) = r*4 + (c ^ ((r>>1)&3)).
__global__ __launch_bounds__(256) void k_qkv(const bf16* __restrict__ w2,
                                             const bf16* __restrict__ xT,
                                             bf16* __restrict__ qT,
                                             bf16* __restrict__ kv){
    __shared__ union {
        struct { bf16 A[4096]; bf16 B[4096]; } st;   // 2 x 8KB, unpadded (global_load_lds)
        bf16 ep[128*130];                            // padded epilogue buffer
    } sm;
    int bid = blockIdx.x;
    int xcd = bid & 7, slot = bid >> 3;
    int m  = slot % 6;
    int ntile = xcd*64 + slot/6;
    int b  = ntile >> 5;
    int n0 = (ntile & 31) * 128;
    int m0 = m * 128;
    int t = threadIdx.x;
    int wv = t >> 6, lane = t & 63;

    // staging addresses: wave wv, instr i -> slots [(wv*2+i)*64 + lane]
    const bf16* gA[2]; const bf16* gB[2];
    bf16* lA[2]; bf16* lB[2];
    #pragma unroll
    for (int i=0;i<2;i++){
        int s = (wv*2+i)*64 + lane;
        int r = s >> 2;
        int c = (s & 3) ^ ((r >> 1) & 3);
        gA[i] = w2 + (size_t)(m0 + r)*CDIM + c*8;
        gB[i] = xT + ((size_t)b*NSP + n0 + r)*CDIM + c*8;
        lA[i] = &sm.st.A[(wv*2+i)*512];   // 64 lanes * 8 bf16
        lB[i] = &sm.st.B[(wv*2+i)*512];
    }
    // fragment LDS addresses (k-invariant)
    const bf16* aAddr[2]; const bf16* bAddr[8];
    #pragma unroll
    for (int mi=0;mi<2;mi++){
        int r = wv*32 + mi*16 + (lane&15);
        int c = lane >> 4;
        aAddr[mi] = &sm.st.A[(r*4 + (c ^ ((r>>1)&3)))*8];
    }
    #pragma unroll
    for (int ni=0;ni<8;ni++){
        int r = ni*16 + (lane&15);
        int c = lane >> 4;
        bAddr[ni] = &sm.st.B[(r*4 + (c ^ ((r>>1)&3)))*8];
    }

    f32x4 acc[2][8];
    #pragma unroll
    for (int i=0;i<16;i++) ((f32x4*)acc)[i] = (f32x4){0.f,0.f,0.f,0.f};

    for (int k0 = 0; k0 < CDIM; k0 += 32){
        __syncthreads();
        #pragma unroll
        for (int i=0;i<2;i++){
            gld16(gA[i] + k0, lA[i]);
            gld16(gB[i] + k0, lB[i]);
        }
        __syncthreads();
        bf16x8 af[2], bfr[8];
        #pragma unroll
        for (int mi=0; mi<2; mi++) af[mi] = *(const bf16x8*)aAddr[mi];
        #pragma unroll
        for (int ni=0; ni<8; ni++) bfr[ni] = *(const bf16x8*)bAddr[ni];
        #pragma unroll
        for (int mi=0; mi<2; mi++)
            #pragma unroll
            for (int ni=0; ni<8; ni++)
                acc[mi][ni] = __builtin_amdgcn_mfma_f32_16x16x32_bf16(af[mi], bfr[ni], acc[mi][ni], 0, 0, 0);
    }
    __syncthreads();   // all waves done with st.A/st.B; safe to overlay ep

    if (m0 < 256){
        // ---- fused q softmax over d (wave's 32 rows == one head): lanes xor 16,32 ----
        #pragma unroll
        for (int ni=0;ni<8;ni++){
            float mx = -1e30f;
            #pragma unroll
            for (int mi=0;mi<2;mi++)
                #pragma unroll
                for (int r=0;r<4;r++) mx = fmaxf(mx, acc[mi][ni][r]);
            mx = fmaxf(mx, __shfl_xor(mx, 16, 64));
            mx = fmaxf(mx, __shfl_xor(mx, 32, 64));
            float s = 0.f;
            #pragma unroll
            for (int mi=0;mi<2;mi++)
                #pragma unroll
                for (int r=0;r<4;r++){
                    float e = __expf(acc[mi][ni][r] - mx);
                    acc[mi][ni][r] = e; s += e;
                }
            s += __shfl_xor(s, 16, 64);
            s += __shfl_xor(s, 32, 64);
            float inv = 1.f/s;
            #pragma unroll
            for (int mi=0;mi<2;mi++)
                #pragma unroll
                for (int r=0;r<4;r++) acc[mi][ni][r] *= inv;
        }
        // dump transposed: ep[n_loc][o_loc]
        #pragma unroll
        for (int mi=0;mi<2;mi++)
            #pragma unroll
            for (int ni=0;ni<8;ni++){
                int n_loc = ni*16 + (lane&15);
                int o_loc = wv*32 + mi*16 + (lane>>4)*4;
                #pragma unroll
                for (int r=0;r<4;r++) sm.ep[n_loc*130 + o_loc + r] = f2bf(acc[mi][ni][r]);
            }
        __syncthreads();
        bf16* qTb = qT + (size_t)b * NSP * CDIM;
        #pragma unroll
        for (int p=0;p<8;p++){
            int task = p*256 + t;
            int n_loc = task >> 4, seg = task & 15;
            bf16x8 v = *(const bf16x8*)&sm.ep[n_loc*130 + seg*8];
            *(bf16x8*)(qTb + (size_t)(n0+n_loc)*CDIM + m0 + seg*8) = v;
        }
    } else {
        if (m0 < 512){
            // ---- fused k softmax over w: 64-col groups (ni 0..3 / 4..7) x 16 lanes ----
            #pragma unroll
            for (int mi=0;mi<2;mi++)
                #pragma unroll
                for (int r=0;r<4;r++)
                    #pragma unroll
                    for (int grp=0;grp<2;grp++){
                        float mx = -1e30f;
                        #pragma unroll
                        for (int q=0;q<4;q++) mx = fmaxf(mx, acc[mi][grp*4+q][r]);
                        #pragma unroll
                        for (int msk=1; msk<16; msk<<=1) mx = fmaxf(mx, __shfl_xor(mx, msk, 64));
                        float s = 0.f;
                        #pragma unroll
                        for (int q=0;q<4;q++){
                            float e = __expf(acc[mi][grp*4+q][r] - mx);
                            acc[mi][grp*4+q][r] = e; s += e;
                        }
                        #pragma unroll
                        for (int msk=1; msk<16; msk<<=1) s += __shfl_xor(s, msk, 64);
                        float inv = 1.f/s;
                        #pragma unroll
                        for (int q=0;q<4;q++) acc[mi][grp*4+q][r] *= inv;
                    }
        }
        // dump: ep[c_loc][n_loc]
        #pragma unroll
        for (int mi=0;mi<2;mi++)
            #pragma unroll
            for (int ni=0;ni<8;ni++){
                int n_loc = ni*16 + (lane&15);
                int c_loc = wv*32 + mi*16 + (lane>>4)*4;
                #pragma unroll
                for (int r=0;r<4;r++) sm.ep[(c_loc+r)*130 + n_loc] = f2bf(acc[mi][ni][r]);
            }
        __syncthreads();
        bf16* kvb = kv + (size_t)b * 512 * NSP;
        int c0t = m0 - 256;
        #pragma unroll
        for (int p=0;p<8;p++){
            int task = p*256 + t;
            int c_loc = task >> 4, seg = task & 15;
            bf16x8 v = *(const bf16x8*)&sm.ep[c_loc*130 + seg*8];
            *(bf16x8*)(kvb + (size_t)(c0t+c_loc)*NSP + n0 + seg*8) = v;
        }
    }
}

// ---------------- K4: ctx partials via MFMA 32x32x16, split-K 16-way ----------------
__global__ __launch_bounds__(256) void k_context(const bf16* __restrict__ kv,
                                                 float* __restrict__ ctx_p){
    int blk = blockIdx.x;
    int bh = blk >> 2;
    int chunk = blk & 3;
    int b = bh >> 3, h = bh & 7;
    int wave = threadIdx.x >> 6, lane = threadIdx.x & 63;
    int nbase = chunk*1024 + wave*256;
    int row = lane & 31;
    int koff = (lane >> 5) * 8;
    const bf16* kp = kv + ((size_t)b*512 +       h*DH + row)*NSP + nbase + koff;
    const bf16* vp = kv + ((size_t)b*512 + 256 + h*DH + row)*NSP + nbase + koff;
    f32x16 acc;
    #pragma unroll
    for (int i=0;i<16;i++) acc[i] = 0.f;
    #pragma unroll
    for (int s=0; s<16; s++){
        bf16x8 a  = *(const bf16x8*)(kp + s*16);
        bf16x8 bb = *(const bf16x8*)(vp + s*16);
        acc = __builtin_amdgcn_mfma_f32_32x32x16_bf16(a, bb, acc, 0, 0, 0);
    }
    float* dst = ctx_p + ((size_t)bh*16 + chunk*4 + wave)*1024;
    #pragma unroll
    for (int r=0;r<16;r++){
        int d = (r&3) + 8*(r>>2) + 4*(lane>>5);
        dst[d*32 + (lane&31)] = acc[r];
    }
}

// ---------------- K5: reduce partials + W2 = w_out x ctx (per b,h) ----------------
__global__ void k_merge(const float* __restrict__ w_out, const float* __restrict__ ctx_p,
                        bf16* __restrict__ W2){
    __shared__ float ctxs[32][32];
    int bh = blockIdx.x;
    int b = bh >> 3, h = bh & 7;
    int t = threadIdx.x;
    const float* base = ctx_p + (size_t)bh*16*1024;
    #pragma unroll
    for (int i=0;i<4;i++){
        int idx = i*256 + t;
        float s = 0.f;
        #pragma unroll
        for (int p=0;p<16;p++) s += base[p*1024 + idx];
        ((float*)ctxs)[idx] = s;
    }
    __syncthreads();
    int o = t;
    const float* wrow = w_out + (size_t)o*CDIM + h*DH;
    float wv[32];
    #pragma unroll
    for (int d=0;d<32;d++) wv[d] = wrow[d];
    bf16* dst = W2 + ((size_t)b*CDIM + o)*CDIM + h*DH;
    #pragma unroll
    for (int g=0;g<4;g++){
        bf16x8 o8;
        #pragma unroll
        for (int jj=0;jj<8;jj++){
            int e = g*8 + jj;
            float s = 0.f;
            #pragma unroll
            for (int d=0;d<32;d++) s += wv[d]*ctxs[d][e];
            o8[jj] = f2bf(s);
        }
        *(bf16x8*)(dst + g*8) = o8;
    }
}

// ---------------- K6: y = W2[b] @ q~T + b_out, then LayerNorm over channels; fp32 out ----------------
#define LDT 40
__global__ __launch_bounds__(256) void k_out_ln(const bf16* __restrict__ W2,
                                                const bf16* __restrict__ qT,
                                                const float* __restrict__ bout,
                                                const float* __restrict__ gamma,
                                                const float* __restrict__ beta,
                                                float* __restrict__ out){
    __shared__ union {
        struct { bf16 As[256*LDT]; bf16 Bs[64*LDT]; } s;
        float Y[256*66];
    } sm;
    __shared__ float red[2][4][64];
    __shared__ float mu_s[64], rstd_s[64];
    int b  = blockIdx.x >> 6;
    int n0 = (blockIdx.x & 63) * 64;
    int t = threadIdx.x, wv = t>>6, lane = t&63;
    f32x4 acc[4][4];
    #pragma unroll
    for (int i=0;i<16;i++) ((f32x4*)acc)[i] = (f32x4){0.f,0.f,0.f,0.f};
    const bf16* Ab = W2 + (size_t)b*CDIM*CDIM;
    const bf16* Bb = qT + ((size_t)b*NSP + n0)*CDIM;
    for (int k0=0; k0<CDIM; k0+=32){
        __syncthreads();
        #pragma unroll
        for (int i=0;i<4;i++){
            int lin = i*256 + t; int r = lin>>2; int c8 = (lin&3)*8;
            *(bf16x8*)&sm.s.As[r*LDT + c8] = *(const bf16x8*)(Ab + (size_t)r*CDIM + k0 + c8);
        }
        { int r = t>>2; int c8 = (t&3)*8;
          *(bf16x8*)&sm.s.Bs[r*LDT + c8] = *(const bf16x8*)(Bb + (size_t)r*CDIM + k0 + c8); }
        __syncthreads();
        bf16x8 af[4], bfr[4];
        #pragma unroll
        for (int mi=0;mi<4;mi++)
            af[mi] = *(const bf16x8*)&sm.s.As[(wv*64 + mi*16 + (lane&15))*LDT + (lane>>4)*8];
        #pragma unroll
        for (int ni=0;ni<4;ni++)
            bfr[ni] = *(const bf16x8*)&sm.s.Bs[(ni*16 + (lane&15))*LDT + (lane>>4)*8];
        #pragma unroll
        for (int mi=0;mi<4;mi++)
            #pragma unroll
            for (int ni=0;ni<4;ni++)
                acc[mi][ni] = __builtin_amdgcn_mfma_f32_16x16x32_bf16(af[mi], bfr[ni], acc[mi][ni], 0, 0, 0);
    }
    __syncthreads();
    #pragma unroll
    for (int mi=0;mi<4;mi++)
        #pragma unroll
        for (int ni=0;ni<4;ni++)
            #pragma unroll
            for (int r=0;r<4;r++){
                int o = wv*64 + mi*16 + (lane>>4)*4 + r;
                int n = ni*16 + (lane&15);
                sm.Y[o*66 + n] = acc[mi][ni][r];
            }
    __syncthreads();
    int n = t & 63, q = t >> 6;
    float s = 0.f, s2 = 0.f;
    for (int o=64*q; o<64*q+64; o++){
        float y = sm.Y[o*66+n] + bout[o];
        s += y; s2 += y*y;
    }
    red[0][q][n] = s; red[1][q][n] = s2;
    __syncthreads();
    if (t < 64){
        float S  = red[0][0][t]+red[0][1][t]+red[0][2][t]+red[0][3][t];
        float S2 = red[1][0][t]+red[1][1][t]+red[1][2][t]+red[1][3][t];
        float mu = S * (1.f/256.f);
        float var = S2*(1.f/256.f) - mu*mu;
        mu_s[t] = mu; rstd_s[t] = rsqrtf(var + 1e-5f);
    }
    __syncthreads();
    float mu = mu_s[n], rstd = rstd_s[n];
    size_t ob = (size_t)b*CDIM*NSP + n0 + n;
    for (int o=64*q; o<64*q+64; o++){
        float y = sm.Y[o*66+n] + bout[o];
        out[ob + (size_t)o*NSP] = (y - mu)*rstd*gamma[o] + beta[o];
    }
}

extern "C" void kernel_launch(void* const* d_in, const int* in_sizes, int n_in,
                              void* d_out, int out_size, void* d_ws, size_t ws_size,
                              hipStream_t stream){
    const float* x     = (const float*)d_in[0];
    const float* w_qkv = (const float*)d_in[1];
    const float* w_out = (const float*)d_in[2];
    const float* b_out = (const float*)d_in[3];
    const float* gamma = (const float*)d_in[4];
    const float* beta  = (const float*)d_in[5];
    float* out = (float*)d_out;
    char* ws = (char*)d_ws;
    // ws layout (bytes):
    //   xT    bf16 [16][4096][256] : 0          .. 33,554,432   (dead after k_qkv)
    //   ctx_p f32  [128][16][1024] : 0          .. 8,388,608    (overlaps dead xT)
    //   qT    bf16 [16][4096][256] : 33,554,432 .. 67,108,864
    //   kv    bf16 [16][512][4096] : 67,108,864 .. 134,217,728
    //   W2    bf16 [16][256][256]  : 134,742,016 .. 136,839,168
    //   w2    bf16 [768][256]      : 136,839,168 .. 137,232,384
    bf16*  xT    = (bf16*) ws;
    float* ctx_p = (float*)ws;
    bf16*  qT    = (bf16*)(ws + 33554432ull);
    bf16*  kv    = (bf16*)(ws + 67108864ull);
    bf16*  W2    = (bf16*)(ws + 134742016ull);
    bf16*  w2    = (bf16*)(ws + 136839168ull);

    k_wcvt     <<<dim3(192),       256, 0, stream>>>(w_qkv, w2);
    k_transpose<<<dim3(64, 4, NB), 256, 0, stream>>>(x, xT);
    k_qkv      <<<dim3(3072),      256, 0, stream>>>(w2, xT, qT, kv);
    k_context  <<<dim3(512),       256, 0, stream>>>(kv, ctx_p);
    k_merge    <<<dim3(128),       256, 0, stream>>>(w_out, ctx_p, W2);
    k_out_ln   <<<dim3(NB*64),     256, 0, stream>>>(W2, qT, b_out, gamma, beta, out);
}

// Round 7
// 248.622 us; speedup vs baseline: 1.8883x; 1.0734x over previous
//
#include <hip/hip_runtime.h>
#include <hip/hip_bf16.h>

#define NB 16
#define CDIM 256
#define NHEADS 8
#define DH 32
#define NSP 4096
#define O3 768

typedef __bf16 bf16;
typedef bf16 bf16x4 __attribute__((ext_vector_type(4)));
typedef bf16 bf16x8 __attribute__((ext_vector_type(8)));
typedef float f32x4 __attribute__((ext_vector_type(4)));
typedef float f32x16 __attribute__((ext_vector_type(16)));

static __device__ __forceinline__ float bf2f(bf16 x){ return (float)x; }
static __device__ __forceinline__ bf16 f2bf(float x){ return (bf16)x; }

// async global->LDS, 16B per lane; lds dst wave-uniform base + lane*16
static __device__ __forceinline__ void gld16(const bf16* g, bf16* l){
    __builtin_amdgcn_global_load_lds((const __attribute__((address_space(1))) void*)g,
                                     (__attribute__((address_space(3))) void*)l, 16, 0, 0);
}

// ---------------- K0: transpose+convert x[b][c][n] (fp32) -> xT[b][n][c] (bf16) ----------------
__global__ void k_transpose(const float* __restrict__ x, bf16* __restrict__ xT){
    __shared__ bf16 tile[64][72];
    int b = blockIdx.z;
    int c0 = blockIdx.y * 64;
    int n0 = blockIdx.x * 64;
    int t = threadIdx.x;
    const float* xb = x + (size_t)b * CDIM * NSP;
    #pragma unroll
    for (int i = 0; i < 4; ++i){
        int lin = i*256 + t;
        int c = lin >> 4;
        int n4 = (lin & 15) * 4;
        f32x4 f = *(const f32x4*)(xb + (size_t)(c0 + c)*NSP + n0 + n4);
        bf16x4 v4;
        #pragma unroll
        for (int j = 0; j < 4; ++j) v4[j] = f2bf(f[j]);
        *(bf16x4*)&tile[c][n4] = v4;
    }
    __syncthreads();
    bf16* xTb = xT + (size_t)b * NSP * CDIM;
    #pragma unroll
    for (int i = 0; i < 2; ++i){
        int lin = i*256 + t;
        int n = lin >> 3;
        int c8 = (lin & 7) * 8;
        bf16x8 v;
        #pragma unroll
        for (int j = 0; j < 8; ++j) v[j] = tile[c8+j][n];
        *(bf16x8*)(xTb + (size_t)(n0+n)*CDIM + c0 + c8) = v;
    }
}

// ---------------- K0b: convert w_qkv fp32 -> bf16 ----------------
__global__ void k_wcvt(const float* __restrict__ w, bf16* __restrict__ w2){
    int idx = (blockIdx.x*256 + threadIdx.x) * 4;
    f32x4 f = *(const f32x4*)(w + idx);
    bf16x4 v;
    #pragma unroll
    for (int j=0;j<4;j++) v[j] = f2bf(f[j]);
    *(bf16x4*)(w2 + idx) = v;
}

// ---------------- K1: qkv GEMM, whole-K B panel in LDS, zero-barrier K-loop ----------------
// B panel: xT[n0..n0+128][0..256] as 128 rows x 32 16B-segments, swizzled:
//   slot(r,c) = r*32 + (c ^ (r&7));  element offset = slot*8.
// A-frags (w2, L2-resident) read directly from global with depth-1 prefetch.
__global__ __launch_bounds__(256) void k_qkv(const bf16* __restrict__ w2,
                                             const bf16* __restrict__ xT,
                                             bf16* __restrict__ qT,
                                             bf16* __restrict__ kv){
    __shared__ union {
        bf16 Bs[32768];       // 128*32 slots * 8 el = 64 KB
        bf16 ep[128*136];     // epilogue buffer (row stride 136 el = 272B, 16B-mult)
    } sm;
    int bid = blockIdx.x;
    int xcd = bid & 7, slot = bid >> 3;
    int m  = slot % 6;
    int ntile = xcd*64 + slot/6;
    int b  = ntile >> 5;
    int n0 = (ntile & 31) * 128;
    int m0 = m * 128;
    int t = threadIdx.x;
    int wv = t >> 6, lane = t & 63;

    // ---- stage whole B panel: per wave 16 gld16 (rows wv*32 .. wv*32+31) ----
    #pragma unroll
    for (int j=0;j<16;j++){
        int base_r = wv*32 + j*2;
        int r = base_r + (lane>>5);
        int c = (lane & 31) ^ (r & 7);
        const bf16* g = xT + ((size_t)b*NSP + n0 + r)*CDIM + c*8;
        gld16(g, &sm.Bs[(size_t)base_r*256]);   // base + lane*16B covers slots base_r*32+lane
    }
    __syncthreads();

    // B-frag slot bases (k-invariant parts)
    int brow[8], brx[8];
    #pragma unroll
    for (int ni=0;ni<8;ni++){
        int r = ni*16 + (lane&15);
        brow[ni] = r*32; brx[ni] = r & 7;
    }
    int arow = m0 + wv*32 + (lane&15);      // + mi*16
    int acol = (lane>>4)*8;                  // + k0*32

    f32x4 acc[2][8];
    #pragma unroll
    for (int i=0;i<16;i++) ((f32x4*)acc)[i] = (f32x4){0.f,0.f,0.f,0.f};

    bf16x8 af0 = *(const bf16x8*)(w2 + (size_t)(arow     )*CDIM + acol);
    bf16x8 af1 = *(const bf16x8*)(w2 + (size_t)(arow + 16)*CDIM + acol);
    #pragma unroll
    for (int k0=0;k0<8;k0++){
        bf16x8 an0, an1;
        if (k0 < 7){
            an0 = *(const bf16x8*)(w2 + (size_t)(arow     )*CDIM + (k0+1)*32 + acol);
            an1 = *(const bf16x8*)(w2 + (size_t)(arow + 16)*CDIM + (k0+1)*32 + acol);
        }
        int cbase = (lane>>4) + k0*4;
        bf16x8 bfr[8];
        #pragma unroll
        for (int ni=0;ni<8;ni++)
            bfr[ni] = *(const bf16x8*)&sm.Bs[(size_t)(brow[ni] + (cbase ^ brx[ni]))*8];
        #pragma unroll
        for (int ni=0;ni<8;ni++)
            acc[0][ni] = __builtin_amdgcn_mfma_f32_16x16x32_bf16(af0, bfr[ni], acc[0][ni], 0, 0, 0);
        #pragma unroll
        for (int ni=0;ni<8;ni++)
            acc[1][ni] = __builtin_amdgcn_mfma_f32_16x16x32_bf16(af1, bfr[ni], acc[1][ni], 0, 0, 0);
        af0 = an0; af1 = an1;
    }
    __syncthreads();   // all waves done with Bs; safe to overlay ep

    if (m0 < 256){
        // ---- fused q softmax over d (wave's 32 rows == one head): lanes xor 16,32 ----
        #pragma unroll
        for (int ni=0;ni<8;ni++){
            float mx = -1e30f;
            #pragma unroll
            for (int mi=0;mi<2;mi++)
                #pragma unroll
                for (int r=0;r<4;r++) mx = fmaxf(mx, acc[mi][ni][r]);
            mx = fmaxf(mx, __shfl_xor(mx, 16, 64));
            mx = fmaxf(mx, __shfl_xor(mx, 32, 64));
            float s = 0.f;
            #pragma unroll
            for (int mi=0;mi<2;mi++)
                #pragma unroll
                for (int r=0;r<4;r++){
                    float e = __expf(acc[mi][ni][r] - mx);
                    acc[mi][ni][r] = e; s += e;
                }
            s += __shfl_xor(s, 16, 64);
            s += __shfl_xor(s, 32, 64);
            float inv = 1.f/s;
            #pragma unroll
            for (int mi=0;mi<2;mi++)
                #pragma unroll
                for (int r=0;r<4;r++) acc[mi][ni][r] *= inv;
        }
        // dump transposed: ep[n_loc][o_loc], b64 stores
        #pragma unroll
        for (int mi=0;mi<2;mi++)
            #pragma unroll
            for (int ni=0;ni<8;ni++){
                int n_loc = ni*16 + (lane&15);
                int o_loc = wv*32 + mi*16 + (lane>>4)*4;
                bf16x4 v4;
                #pragma unroll
                for (int r=0;r<4;r++) v4[r] = f2bf(acc[mi][ni][r]);
                *(bf16x4*)&sm.ep[n_loc*136 + o_loc] = v4;
            }
        __syncthreads();
        bf16* qTb = qT + (size_t)b * NSP * CDIM;
        #pragma unroll
        for (int p=0;p<8;p++){
            int task = p*256 + t;
            int n_loc = task >> 4, seg = task & 15;
            bf16x8 v = *(const bf16x8*)&sm.ep[n_loc*136 + seg*8];
            *(bf16x8*)(qTb + (size_t)(n0+n_loc)*CDIM + m0 + seg*8) = v;
        }
    } else {
        if (m0 < 512){
            // ---- fused k softmax over w: 64-col groups (ni 0..3 / 4..7) x 16 lanes ----
            #pragma unroll
            for (int mi=0;mi<2;mi++)
                #pragma unroll
                for (int r=0;r<4;r++)
                    #pragma unroll
                    for (int grp=0;grp<2;grp++){
                        float mx = -1e30f;
                        #pragma unroll
                        for (int q=0;q<4;q++) mx = fmaxf(mx, acc[mi][grp*4+q][r]);
                        #pragma unroll
                        for (int msk=1; msk<16; msk<<=1) mx = fmaxf(mx, __shfl_xor(mx, msk, 64));
                        float s = 0.f;
                        #pragma unroll
                        for (int q=0;q<4;q++){
                            float e = __expf(acc[mi][grp*4+q][r] - mx);
                            acc[mi][grp*4+q][r] = e; s += e;
                        }
                        #pragma unroll
                        for (int msk=1; msk<16; msk<<=1) s += __shfl_xor(s, msk, 64);
                        float inv = 1.f/s;
                        #pragma unroll
                        for (int q=0;q<4;q++) acc[mi][grp*4+q][r] *= inv;
                    }
        }
        // dump: ep[c_loc][n_loc]
        #pragma unroll
        for (int mi=0;mi<2;mi++)
            #pragma unroll
            for (int ni=0;ni<8;ni++){
                int n_loc = ni*16 + (lane&15);
                int c_loc = wv*32 + mi*16 + (lane>>4)*4;
                #pragma unroll
                for (int r=0;r<4;r++) sm.ep[(c_loc+r)*136 + n_loc] = f2bf(acc[mi][ni][r]);
            }
        __syncthreads();
        bf16* kvb = kv + (size_t)b * 512 * NSP;
        int c0t = m0 - 256;
        #pragma unroll
        for (int p=0;p<8;p++){
            int task = p*256 + t;
            int c_loc = task >> 4, seg = task & 15;
            bf16x8 v = *(const bf16x8*)&sm.ep[c_loc*136 + seg*8];
            *(bf16x8*)(kvb + (size_t)(c0t+c_loc)*NSP + n0 + seg*8) = v;
        }
    }
}

// ---------------- K4: ctx partials via MFMA 32x32x16, split-K 16-way ----------------
__global__ __launch_bounds__(256) void k_context(const bf16* __restrict__ kv,
                                                 float* __restrict__ ctx_p){
    int blk = blockIdx.x;
    int bh = blk >> 2;
    int chunk = blk & 3;
    int b = bh >> 3, h = bh & 7;
    int wave = threadIdx.x >> 6, lane = threadIdx.x & 63;
    int nbase = chunk*1024 + wave*256;
    int row = lane & 31;
    int koff = (lane >> 5) * 8;
    const bf16* kp = kv + ((size_t)b*512 +       h*DH + row)*NSP + nbase + koff;
    const bf16* vp = kv + ((size_t)b*512 + 256 + h*DH + row)*NSP + nbase + koff;
    f32x16 acc;
    #pragma unroll
    for (int i=0;i<16;i++) acc[i] = 0.f;
    #pragma unroll
    for (int s=0; s<16; s++){
        bf16x8 a  = *(const bf16x8*)(kp + s*16);
        bf16x8 bb = *(const bf16x8*)(vp + s*16);
        acc = __builtin_amdgcn_mfma_f32_32x32x16_bf16(a, bb, acc, 0, 0, 0);
    }
    float* dst = ctx_p + ((size_t)bh*16 + chunk*4 + wave)*1024;
    #pragma unroll
    for (int r=0;r<16;r++){
        int d = (r&3) + 8*(r>>2) + 4*(lane>>5);
        dst[d*32 + (lane&31)] = acc[r];
    }
}

// ---------------- K5: reduce partials + W2 = w_out x ctx (per b,h) ----------------
__global__ void k_merge(const float* __restrict__ w_out, const float* __restrict__ ctx_p,
                        bf16* __restrict__ W2){
    __shared__ float ctxs[32][32];
    int bh = blockIdx.x;
    int b = bh >> 3, h = bh & 7;
    int t = threadIdx.x;
    const float* base = ctx_p + (size_t)bh*16*1024;
    #pragma unroll
    for (int i=0;i<4;i++){
        int idx = i*256 + t;
        float s = 0.f;
        #pragma unroll
        for (int p=0;p<16;p++) s += base[p*1024 + idx];
        ((float*)ctxs)[idx] = s;
    }
    __syncthreads();
    int o = t;
    const float* wrow = w_out + (size_t)o*CDIM + h*DH;
    float wv[32];
    #pragma unroll
    for (int d=0;d<32;d++) wv[d] = wrow[d];
    bf16* dst = W2 + ((size_t)b*CDIM + o)*CDIM + h*DH;
    #pragma unroll
    for (int g=0;g<4;g++){
        bf16x8 o8;
        #pragma unroll
        for (int jj=0;jj<8;jj++){
            int e = g*8 + jj;
            float s = 0.f;
            #pragma unroll
            for (int d=0;d<32;d++) s += wv[d]*ctxs[d][e];
            o8[jj] = f2bf(s);
        }
        *(bf16x8*)(dst + g*8) = o8;
    }
}

// ---------------- K6: y = W2[b] @ q~T + b_out + LayerNorm; whole-K panel, few barriers ----------------
__global__ __launch_bounds__(256) void k_out_ln(const bf16* __restrict__ W2,
                                                const bf16* __restrict__ qT,
                                                const float* __restrict__ bout,
                                                const float* __restrict__ gamma,
                                                const float* __restrict__ beta,
                                                float* __restrict__ out){
    __shared__ union {
        bf16 Bs[16384];      // 64 rows * 32 slots * 8 el = 32 KB
        float Y[256*66];     // 67.6 KB
    } sm;
    __shared__ float red[2][4][64];
    __shared__ float mu_s[64], rstd_s[64];
    int bid = blockIdx.x;
    int xcd = bid & 7, slot = bid >> 3;      // 128 slots
    int b  = slot >> 3;
    int n0 = (xcd*8 + (slot & 7)) * 64;
    int t = threadIdx.x, wv = t>>6, lane = t&63;

    // ---- stage qT panel [n0..n0+64][0..256]: per wave 8 gld16 (rows wv*16..wv*16+15) ----
    const bf16* qTb = qT + (size_t)b * NSP * CDIM;
    #pragma unroll
    for (int j=0;j<8;j++){
        int base_r = wv*16 + j*2;
        int r = base_r + (lane>>5);
        int c = (lane & 31) ^ (r & 7);
        gld16(qTb + (size_t)(n0 + r)*CDIM + c*8, &sm.Bs[(size_t)base_r*256]);
    }
    __syncthreads();

    int brow[4], brx[4];
    #pragma unroll
    for (int ni=0;ni<4;ni++){
        int r = ni*16 + (lane&15);
        brow[ni] = r*32; brx[ni] = r & 7;
    }
    const bf16* Ab = W2 + (size_t)b*CDIM*CDIM;
    int arow = wv*64 + (lane&15);
    int acol = (lane>>4)*8;

    f32x4 acc[4][4];
    #pragma unroll
    for (int i=0;i<16;i++) ((f32x4*)acc)[i] = (f32x4){0.f,0.f,0.f,0.f};

    bf16x8 af[4], an[4];
    #pragma unroll
    for (int mi=0;mi<4;mi++)
        af[mi] = *(const bf16x8*)(Ab + (size_t)(arow + mi*16)*CDIM + acol);
    #pragma unroll 2
    for (int k0=0;k0<8;k0++){
        if (k0 < 7){
            #pragma unroll
            for (int mi=0;mi<4;mi++)
                an[mi] = *(const bf16x8*)(Ab + (size_t)(arow + mi*16)*CDIM + (k0+1)*32 + acol);
        }
        int cbase = (lane>>4) + k0*4;
        bf16x8 bfr[4];
        #pragma unroll
        for (int ni=0;ni<4;ni++)
            bfr[ni] = *(const bf16x8*)&sm.Bs[(size_t)(brow[ni] + (cbase ^ brx[ni]))*8];
        #pragma unroll
        for (int mi=0;mi<4;mi++)
            #pragma unroll
            for (int ni=0;ni<4;ni++)
                acc[mi][ni] = __builtin_amdgcn_mfma_f32_16x16x32_bf16(af[mi], bfr[ni], acc[mi][ni], 0, 0, 0);
        #pragma unroll
        for (int mi=0;mi<4;mi++) af[mi] = an[mi];
    }
    __syncthreads();   // done with Bs; overlay Y
    #pragma unroll
    for (int mi=0;mi<4;mi++)
        #pragma unroll
        for (int ni=0;ni<4;ni++)
            #pragma unroll
            for (int r=0;r<4;r++){
                int o = wv*64 + mi*16 + (lane>>4)*4 + r;
                int n = ni*16 + (lane&15);
                sm.Y[o*66 + n] = acc[mi][ni][r];
            }
    __syncthreads();
    int n = t & 63, q = t >> 6;
    float s = 0.f, s2 = 0.f;
    for (int o=64*q; o<64*q+64; o++){
        float y = sm.Y[o*66+n] + bout[o];
        s += y; s2 += y*y;
    }
    red[0][q][n] = s; red[1][q][n] = s2;
    __syncthreads();
    if (t < 64){
        float S  = red[0][0][t]+red[0][1][t]+red[0][2][t]+red[0][3][t];
        float S2 = red[1][0][t]+red[1][1][t]+red[1][2][t]+red[1][3][t];
        float mu = S * (1.f/256.f);
        float var = S2*(1.f/256.f) - mu*mu;
        mu_s[t] = mu; rstd_s[t] = rsqrtf(var + 1e-5f);
    }
    __syncthreads();
    float mu = mu_s[n], rstd = rstd_s[n];
    size_t ob = (size_t)b*CDIM*NSP + n0 + n;
    for (int o=64*q; o<64*q+64; o++){
        float y = sm.Y[o*66+n] + bout[o];
        out[ob + (size_t)o*NSP] = (y - mu)*rstd*gamma[o] + beta[o];
    }
}

extern "C" void kernel_launch(void* const* d_in, const int* in_sizes, int n_in,
                              void* d_out, int out_size, void* d_ws, size_t ws_size,
                              hipStream_t stream){
    const float* x     = (const float*)d_in[0];
    const float* w_qkv = (const float*)d_in[1];
    const float* w_out = (const float*)d_in[2];
    const float* b_out = (const float*)d_in[3];
    const float* gamma = (const float*)d_in[4];
    const float* beta  = (const float*)d_in[5];
    float* out = (float*)d_out;
    char* ws = (char*)d_ws;
    // ws layout (bytes):
    //   xT    bf16 [16][4096][256] : 0          .. 33,554,432   (dead after k_qkv)
    //   ctx_p f32  [128][16][1024] : 0          .. 8,388,608    (overlaps dead xT)
    //   qT    bf16 [16][4096][256] : 33,554,432 .. 67,108,864
    //   kv    bf16 [16][512][4096] : 67,108,864 .. 134,217,728
    //   W2    bf16 [16][256][256]  : 134,742,016 .. 136,839,168
    //   w2    bf16 [768][256]      : 136,839,168 .. 137,232,384
    bf16*  xT    = (bf16*) ws;
    float* ctx_p = (float*)ws;
    bf16*  qT    = (bf16*)(ws + 33554432ull);
    bf16*  kv    = (bf16*)(ws + 67108864ull);
    bf16*  W2    = (bf16*)(ws + 134742016ull);
    bf16*  w2    = (bf16*)(ws + 136839168ull);

    k_wcvt     <<<dim3(192),       256, 0, stream>>>(w_qkv, w2);
    k_transpose<<<dim3(64, 4, NB), 256, 0, stream>>>(x, xT);
    k_qkv      <<<dim3(3072),      256, 0, stream>>>(w2, xT, qT, kv);
    k_context  <<<dim3(512),       256, 0, stream>>>(kv, ctx_p);
    k_merge    <<<dim3(128),       256, 0, stream>>>(w_out, ctx_p, W2);
    k_out_ln   <<<dim3(1024),      256, 0, stream>>>(W2, qT, b_out, gamma, beta, out);
}